// Round 10
// baseline (258.261 us; speedup 1.0000x reference)
//
#include <hip/hip_runtime.h>
#include <hip/hip_bf16.h>
#include <cstdint>
#include <cstddef>

// Causal self-attention, B=2 S=2048 E=1024 H=16 D=64.
// Inputs fp32, output fp32, ws intermediates bf16.
// Round 10: attn_v4 = round-8 attn_v3 structure (best measured, 130us) +
// (1) XCD-balanced qg mapping (old pairing skewed per-XCD work 4x via bid%8
//     round-robin -> slowest-XCD-bound, 22% occupancy), and
// (2) K fragment loads hoisted before the staging barrier (vmcnt drain at the
//     barrier covers K latency; compute starts with K in regs).
// GEMMs + vtrans unchanged.

#define B_  2
#define S_  2048
#define E_  1024
#define NH_ 16
#define DH_ 64
#define M_  (B_*S_)      // 4096
#define F_  (NH_*DH_)    // 1024

typedef unsigned short u16;
typedef short short8 __attribute__((ext_vector_type(8)));
typedef float f32x4  __attribute__((ext_vector_type(4)));

__device__ __forceinline__ float bf2f(u16 u) {
    union { unsigned int i; float f; } c; c.i = ((unsigned int)u) << 16; return c.f;
}
__device__ __forceinline__ u16 f2bf(float f) {
    union { float f; unsigned int i; } c; c.f = f;
    unsigned int x = c.i;
    x += 0x7fffu + ((x >> 16) & 1u);   // RNE
    return (u16)(x >> 16);
}

// ---------------------------------------------------------------------------
// MFMA GEMM (unchanged). 128x128 tile, BK=64, 4 waves.
// ---------------------------------------------------------------------------
template<int MODE>
__global__ __launch_bounds__(256)
void mfma_gemm(const void* __restrict__ Araw,
               const float* __restrict__ W0, const float* __restrict__ W1,
               const float* __restrict__ W2,
               void* __restrict__ Out0, void* __restrict__ Out1,
               void* __restrict__ Out2)
{
    __shared__ __align__(16) char lds[32768];
    char* lA = lds;
    char* lB = lds + 16384;

    const int tid = threadIdx.x;
    const int lane = tid & 63;
    const int w    = tid >> 6;
    const int wr   = w >> 1, wc = w & 1;
    const int g    = lane >> 4;
    const int q15  = lane & 15;
    const int bx   = blockIdx.x;
    const int by   = blockIdx.y;
    const int z    = (MODE == 0) ? blockIdx.z : 0;

    const float* W   = (z == 0) ? W0 : (z == 1) ? W1 : W2;
    void*        Out = (z == 0) ? Out0 : (z == 1) ? Out1 : Out2;

    const int sArow = tid >> 1;
    const int sAseg = (tid & 1) * 32;
    const int sBkb  = (tid >> 2) & 7;
    const int sBcb  = (tid >> 5) * 4 + (tid & 3);

    f32x4 acc[4][4];
    #pragma unroll
    for (int i = 0; i < 4; ++i)
        #pragma unroll
        for (int j = 0; j < 4; ++j) acc[i][j] = (f32x4){0.f,0.f,0.f,0.f};

    float4 pa[8];
    short8 pa2[4];
    float4 pb[8];

    const int aRow = by*128 + sArow;
    const int ab   = aRow >> 11, as = aRow & (S_-1);

    auto LOADA = [&](int k0) {
        if (MODE == 0) {
            const float* ap = (const float*)Araw + (size_t)aRow * E_ + k0 + sAseg;
            #pragma unroll
            for (int u = 0; u < 8; ++u) pa[u] = ((const float4*)ap)[u];
        } else {
            int h = k0 >> 6;
            const u16* ap = (const u16*)Araw +
                (((size_t)ab*NH_ + h)*S_ + as)*DH_ + sAseg;
            #pragma unroll
            for (int u = 0; u < 4; ++u) pa2[u] = ((const short8*)ap)[u];
        }
    };
    auto LOADB = [&](int k0) {
        const float* bp = W + (size_t)(k0 + sBkb*8) * F_ + bx*128 + sBcb*4;
        #pragma unroll
        for (int j = 0; j < 8; ++j) pb[j] = *(const float4*)(bp + (size_t)j * F_);
    };
    auto WRITEA = [&]() {
        #pragma unroll
        for (int c = 0; c < 4; ++c) {
            short8 ch;
            if (MODE == 0) {
                const float* f0 = (const float*)&pa[2*c];
                #pragma unroll
                for (int j = 0; j < 8; ++j) ((u16*)&ch)[j] = f2bf(f0[j]);
            } else ch = pa2[c];
            *(short8*)(lA + sArow*128 + ((sAseg*2 + 16*c) ^ ((sArow&7)<<4))) = ch;
        }
    };
    auto WRITEB = [&]() {
        #pragma unroll
        for (int c = 0; c < 4; ++c) {
            short8 bs;
            #pragma unroll
            for (int j = 0; j < 8; ++j)
                ((u16*)&bs)[j] = f2bf(((const float*)&pb[j])[c]);
            int n = sBcb*4 + c;
            *(short8*)(lB + n*128 + ((16*sBkb) ^ ((n&7)<<4))) = bs;
        }
    };

    LOADA(0); LOADB(0);

    for (int it = 0; it < E_/64; ++it) {
        __syncthreads();
        WRITEA(); WRITEB();
        __syncthreads();
        if (it + 1 < E_/64) { LOADA((it+1)*64); LOADB((it+1)*64); }
        #pragma unroll
        for (int s = 0; s < 2; ++s) {
            short8 af[4], bfr[4];
            #pragma unroll
            for (int mt = 0; mt < 4; ++mt) {
                int row = wr*64 + mt*16 + q15;
                af[mt] = *(const short8*)(lA + row*128 + ((s*64 + 16*g) ^ ((row&7)<<4)));
            }
            #pragma unroll
            for (int nt = 0; nt < 4; ++nt) {
                int n = wc*64 + nt*16 + q15;
                bfr[nt] = *(const short8*)(lB + n*128 + ((s*64 + 16*g) ^ ((n&7)<<4)));
            }
            #pragma unroll
            for (int mt = 0; mt < 4; ++mt)
                #pragma unroll
                for (int nt = 0; nt < 4; ++nt)
                    acc[mt][nt] = __builtin_amdgcn_mfma_f32_16x16x32_bf16(
                        af[mt], bfr[nt], acc[mt][nt], 0, 0, 0);
        }
    }

    #pragma unroll
    for (int mt = 0; mt < 4; ++mt) {
        #pragma unroll
        for (int r = 0; r < 4; ++r) {
            int grow = by*128 + wr*64 + mt*16 + 4*g + r;
            if (MODE == 0) {
                int bb = grow >> 11, ss = grow & (S_-1);
                #pragma unroll
                for (int nt = 0; nt < 4; ++nt) {
                    int n = bx*128 + wc*64 + nt*16 + q15;
                    int hh = n >> 6, dd = n & 63;
                    ((u16*)Out)[(((size_t)bb*NH_ + hh)*S_ + ss)*DH_ + dd] =
                        f2bf(acc[mt][nt][r]);
                }
            } else {
                #pragma unroll
                for (int nt = 0; nt < 4; ++nt) {
                    int n = bx*128 + wc*64 + nt*16 + q15;
                    ((float*)Out)[(size_t)grow * F_ + n] = acc[mt][nt][r];
                }
            }
        }
    }
}

// ---------------------------------------------------------------------------
// V transpose: [b][h][s][d] -> Vt [b][h][d][s] (unchanged).
// ---------------------------------------------------------------------------
__global__ __launch_bounds__(256)
void vtrans(const u16* __restrict__ V, u16* __restrict__ Vt)
{
    __shared__ u16 t[64][66];
    const int tid = threadIdx.x;
    const int st  = blockIdx.x;
    const int bh  = blockIdx.y;

    {
        int s = tid >> 2, dseg = (tid & 3) * 16;
        const u16* src = V + ((size_t)bh*S_ + st*64 + s)*DH_ + dseg;
        short8 a = ((const short8*)src)[0];
        short8 b = ((const short8*)src)[1];
        *(short8*)&t[s][dseg]     = a;
        *(short8*)&t[s][dseg + 8] = b;
    }
    __syncthreads();
    {
        int d = tid >> 2, sseg = (tid & 3) * 16;
        short8 o0, o1;
        #pragma unroll
        for (int i = 0; i < 8; ++i) ((u16*)&o0)[i] = t[sseg + i][d];
        #pragma unroll
        for (int i = 0; i < 8; ++i) ((u16*)&o1)[i] = t[sseg + 8 + i][d];
        u16* dst = Vt + ((size_t)bh*DH_ + d)*S_ + st*64 + sseg;
        ((short8*)dst)[0] = o0;
        ((short8*)dst)[1] = o1;
    }
}

// ---------------------------------------------------------------------------
// attn_v4: round-8 v3 structure + XCD-balanced qg mapping + hoisted K loads.
// Q,K: [b][h][s][d]; Vt: [b][h][d][s]. O overwrites own Q rows.
// ---------------------------------------------------------------------------
__global__ __launch_bounds__(256)
void attn_v4(const u16* Q, const u16* __restrict__ K,
             const u16* __restrict__ Vt, u16* O)
{
    __shared__ u16 vt[64*64];       // V^T tile [d][key], swizzled, 8 KB
    __shared__ u16 pl[4][16*64];    // per-wave P [q][key], swizzled, 8 KB

    const int tid  = threadIdx.x;
    const int lane = tid & 63;
    const int w    = tid >> 6;
    const int g    = lane >> 4;
    const int q15  = lane & 15;

    const int blk = blockIdx.x;
    const int tq  = blk & 31;
    const int bh  = blk >> 5;

    // XCD-balanced q-tile mapping: per residue class (tq&7) the four rounds
    // give qg = {2c, 31-2c, 2c+1, 30-2c}, sum 62 for every XCD.
    const int rr_ = tq >> 3, cc_ = tq & 7;
    int qg;
    if      (rr_ == 0) qg = 2*cc_;
    else if (rr_ == 1) qg = 31 - 2*cc_;
    else if (rr_ == 2) qg = 2*cc_ + 1;
    else               qg = 30 - 2*cc_;

    const int q0  = qg * 64;

    const u16* Kb  = K  + (size_t)bh * S_ * DH_;
    const u16* Vtb = Vt + (size_t)bh * DH_ * S_;

    short8 qf0, qf1;
    {
        const u16* Qp = Q + ((size_t)bh * S_ + q0 + w*16 + q15) * DH_ + g*8;
        qf0 = *(const short8*)(Qp);
        qf1 = *(const short8*)(Qp + 32);
    }

    f32x4 o[4];
    #pragma unroll
    for (int dt = 0; dt < 4; ++dt) o[dt] = (f32x4){0.f,0.f,0.f,0.f};
    float mrow = -1e30f, lrow = 0.f;

    char* plw = (char*)&pl[w][0];
    const int sd = tid >> 2;           // staging d row 0..63
    const int sk = (tid & 3) * 32;     // staging key-chunk byte offset

    for (int kt = 0; kt <= qg; ++kt) {
        __syncthreads();
        // ---- issue V staging loads, then K fragment loads (both in flight) ----
        const u16* vs = Vtb + (size_t)sd * S_ + kt*64 + (sk >> 1);
        short8 va = ((const short8*)vs)[0];
        short8 vb = ((const short8*)vs)[1];
        short8 kf[8];
        {
            const u16* Kp = Kb + (size_t)(kt*64 + q15) * DH_ + g*8;
            #pragma unroll
            for (int t = 0; t < 4; ++t) {
                kf[2*t]   = *(const short8*)(Kp + (size_t)t*16*DH_);
                kf[2*t+1] = *(const short8*)(Kp + (size_t)t*16*DH_ + 32);
            }
        }
        {
            char* dst = (char*)vt + sd*128;
            *(short8*)(dst + ((sk     ) ^ ((sd&7)<<4))) = va;
            *(short8*)(dst + ((sk + 16) ^ ((sd&7)<<4))) = vb;
        }
        __syncthreads();   // drains vmcnt: V in LDS, K in regs

        // ---- QK^T from prefetched K regs ----
        float p[16];
        #pragma unroll
        for (int t = 0; t < 4; ++t) {
            f32x4 st = (f32x4){0.f,0.f,0.f,0.f};
            st = __builtin_amdgcn_mfma_f32_16x16x32_bf16(kf[2*t],   qf0, st, 0, 0, 0);
            st = __builtin_amdgcn_mfma_f32_16x16x32_bf16(kf[2*t+1], qf1, st, 0, 0, 0);
            #pragma unroll
            for (int r = 0; r < 4; ++r) p[t*4+r] = st[r] * 0.125f;
        }

        // causal mask (diagonal tile only)
        if (kt == qg) {
            #pragma unroll
            for (int t = 0; t < 4; ++t)
                #pragma unroll
                for (int r = 0; r < 4; ++r)
                    if (16*t + 4*g + r > w*16 + q15) p[t*4+r] = -1e30f;
        }

        // ---- online softmax ----
        float tmax = p[0];
        #pragma unroll
        for (int i = 1; i < 16; ++i) tmax = fmaxf(tmax, p[i]);
        tmax = fmaxf(tmax, __shfl_xor(tmax, 16));
        tmax = fmaxf(tmax, __shfl_xor(tmax, 32));
        float mnew = fmaxf(mrow, tmax);
        float rsc  = __expf(mrow - mnew);
        mrow = mnew;
        float psum = 0.f;
        #pragma unroll
        for (int i = 0; i < 16; ++i) { p[i] = __expf(p[i] - mnew); psum += p[i]; }
        psum += __shfl_xor(psum, 16);
        psum += __shfl_xor(psum, 32);
        lrow = lrow * rsc + psum;

        #pragma unroll
        for (int r = 0; r < 4; ++r) {
            float rr2 = __shfl(rsc, 4*g + r);
            #pragma unroll
            for (int dt = 0; dt < 4; ++dt) o[dt][r] *= rr2;
        }

        // ---- P -> bf16 -> per-wave LDS ----
        #pragma unroll
        for (int t = 0; t < 4; ++t) {
            ushort4 pw;
            pw.x = f2bf(p[t*4+0]); pw.y = f2bf(p[t*4+1]);
            pw.z = f2bf(p[t*4+2]); pw.w = f2bf(p[t*4+3]);
            int byte = q15*128 + ((32*t + 8*g) ^ ((q15&7)<<4));
            *(ushort4*)(plw + byte) = pw;
        }

        // ---- PV: swizzled b128 LDS reads ----
        #pragma unroll
        for (int c = 0; c < 2; ++c) {
            int pb = q15*128 + ((64*c + 16*g) ^ ((q15&7)<<4));
            short8 pf = *(const short8*)(plw + pb);
            #pragma unroll
            for (int dt = 0; dt < 4; ++dt) {
                int d = dt*16 + q15;
                int vb = d*128 + ((64*c + 16*g) ^ ((d&7)<<4));
                short8 vf = *(const short8*)((char*)vt + vb);
                o[dt] = __builtin_amdgcn_mfma_f32_16x16x32_bf16(pf, vf, o[dt], 0, 0, 0);
            }
        }
    }

    // ---- epilogue ----
    float inv = 1.f / lrow;
    #pragma unroll
    for (int r = 0; r < 4; ++r) {
        float li = __shfl(inv, 4*g + r);
        int qrow = q0 + w*16 + 4*g + r;
        #pragma unroll
        for (int dt = 0; dt < 4; ++dt) {
            O[((size_t)bh * S_ + qrow) * DH_ + dt*16 + q15] = f2bf(o[dt][r] * li);
        }
    }
}

// ---------------------------------------------------------------------------
extern "C" void kernel_launch(void* const* d_in, const int* in_sizes, int n_in,
                              void* d_out, int out_size, void* d_ws, size_t ws_size,
                              hipStream_t stream) {
    (void)in_sizes; (void)n_in; (void)out_size; (void)ws_size;
    const float* x  = (const float*)d_in[0];
    const float* wq = (const float*)d_in[1];
    const float* wk = (const float*)d_in[2];
    const float* wv = (const float*)d_in[3];
    const float* wo = (const float*)d_in[4];

    u16* Qw = (u16*)d_ws;                    // [B][H][S][D] bf16 (O reuses)
    u16* Kw = Qw + (size_t)M_ * F_;
    u16* Vw = Kw + (size_t)M_ * F_;          // ws total 24 MiB
    u16* Vt = (u16*)d_out;                   // scratch; overwritten by oproj

    mfma_gemm<0><<<dim3(F_/128, M_/128, 3), 256, 0, stream>>>(
        (const void*)x, wq, wk, wv, (void*)Qw, (void*)Kw, (void*)Vw);
    vtrans<<<dim3(S_/64, B_*NH_), 256, 0, stream>>>(Vw, Vt);
    attn_v4<<<dim3(B_*NH_*(S_/64)), 256, 0, stream>>>(Qw, Kw, Vt, Qw);
    mfma_gemm<2><<<dim3(F_/128, M_/128, 1), 256, 0, stream>>>(
        (const void*)Qw, wo, wo, wo, d_out, d_out, d_out);
}

// Round 11
// 191.311 us; speedup vs baseline: 1.3500x; 1.3500x over previous
//
#include <hip/hip_runtime.h>
#include <hip/hip_bf16.h>
#include <cstdint>
#include <cstddef>

// Causal self-attention, B=2 S=2048 E=1024 H=16 D=64.
// Inputs fp32, output fp32, ws intermediates bf16.
// Round 11: attn_v6 = cross-iteration software pipeline. K AND V tiles in
// double-buffered LDS; all global loads for tile kt+1 issued at the TOP of
// iter kt (reg-staged, T14), LDS writes at the bottom, one barrier/iter.
// Compute bodies (QK^T, softmax, P path, mask, epilogue) identical to the
// verified round-8 attn_v3. GEMMs + vtrans unchanged.

#define B_  2
#define S_  2048
#define E_  1024
#define NH_ 16
#define DH_ 64
#define M_  (B_*S_)      // 4096
#define F_  (NH_*DH_)    // 1024

typedef unsigned short u16;
typedef short short8 __attribute__((ext_vector_type(8)));
typedef float f32x4  __attribute__((ext_vector_type(4)));

__device__ __forceinline__ float bf2f(u16 u) {
    union { unsigned int i; float f; } c; c.i = ((unsigned int)u) << 16; return c.f;
}
__device__ __forceinline__ u16 f2bf(float f) {
    union { float f; unsigned int i; } c; c.f = f;
    unsigned int x = c.i;
    x += 0x7fffu + ((x >> 16) & 1u);   // RNE
    return (u16)(x >> 16);
}

// ---------------------------------------------------------------------------
// MFMA GEMM (unchanged). 128x128 tile, BK=64, 4 waves.
// ---------------------------------------------------------------------------
template<int MODE>
__global__ __launch_bounds__(256)
void mfma_gemm(const void* __restrict__ Araw,
               const float* __restrict__ W0, const float* __restrict__ W1,
               const float* __restrict__ W2,
               void* __restrict__ Out0, void* __restrict__ Out1,
               void* __restrict__ Out2)
{
    __shared__ __align__(16) char lds[32768];
    char* lA = lds;
    char* lB = lds + 16384;

    const int tid = threadIdx.x;
    const int lane = tid & 63;
    const int w    = tid >> 6;
    const int wr   = w >> 1, wc = w & 1;
    const int g    = lane >> 4;
    const int q15  = lane & 15;
    const int bx   = blockIdx.x;
    const int by   = blockIdx.y;
    const int z    = (MODE == 0) ? blockIdx.z : 0;

    const float* W   = (z == 0) ? W0 : (z == 1) ? W1 : W2;
    void*        Out = (z == 0) ? Out0 : (z == 1) ? Out1 : Out2;

    const int sArow = tid >> 1;
    const int sAseg = (tid & 1) * 32;
    const int sBkb  = (tid >> 2) & 7;
    const int sBcb  = (tid >> 5) * 4 + (tid & 3);

    f32x4 acc[4][4];
    #pragma unroll
    for (int i = 0; i < 4; ++i)
        #pragma unroll
        for (int j = 0; j < 4; ++j) acc[i][j] = (f32x4){0.f,0.f,0.f,0.f};

    float4 pa[8];
    short8 pa2[4];
    float4 pb[8];

    const int aRow = by*128 + sArow;
    const int ab   = aRow >> 11, as = aRow & (S_-1);

    auto LOADA = [&](int k0) {
        if (MODE == 0) {
            const float* ap = (const float*)Araw + (size_t)aRow * E_ + k0 + sAseg;
            #pragma unroll
            for (int u = 0; u < 8; ++u) pa[u] = ((const float4*)ap)[u];
        } else {
            int h = k0 >> 6;
            const u16* ap = (const u16*)Araw +
                (((size_t)ab*NH_ + h)*S_ + as)*DH_ + sAseg;
            #pragma unroll
            for (int u = 0; u < 4; ++u) pa2[u] = ((const short8*)ap)[u];
        }
    };
    auto LOADB = [&](int k0) {
        const float* bp = W + (size_t)(k0 + sBkb*8) * F_ + bx*128 + sBcb*4;
        #pragma unroll
        for (int j = 0; j < 8; ++j) pb[j] = *(const float4*)(bp + (size_t)j * F_);
    };
    auto WRITEA = [&]() {
        #pragma unroll
        for (int c = 0; c < 4; ++c) {
            short8 ch;
            if (MODE == 0) {
                const float* f0 = (const float*)&pa[2*c];
                #pragma unroll
                for (int j = 0; j < 8; ++j) ((u16*)&ch)[j] = f2bf(f0[j]);
            } else ch = pa2[c];
            *(short8*)(lA + sArow*128 + ((sAseg*2 + 16*c) ^ ((sArow&7)<<4))) = ch;
        }
    };
    auto WRITEB = [&]() {
        #pragma unroll
        for (int c = 0; c < 4; ++c) {
            short8 bs;
            #pragma unroll
            for (int j = 0; j < 8; ++j)
                ((u16*)&bs)[j] = f2bf(((const float*)&pb[j])[c]);
            int n = sBcb*4 + c;
            *(short8*)(lB + n*128 + ((16*sBkb) ^ ((n&7)<<4))) = bs;
        }
    };

    LOADA(0); LOADB(0);

    for (int it = 0; it < E_/64; ++it) {
        __syncthreads();
        WRITEA(); WRITEB();
        __syncthreads();
        if (it + 1 < E_/64) { LOADA((it+1)*64); LOADB((it+1)*64); }
        #pragma unroll
        for (int s = 0; s < 2; ++s) {
            short8 af[4], bfr[4];
            #pragma unroll
            for (int mt = 0; mt < 4; ++mt) {
                int row = wr*64 + mt*16 + q15;
                af[mt] = *(const short8*)(lA + row*128 + ((s*64 + 16*g) ^ ((row&7)<<4)));
            }
            #pragma unroll
            for (int nt = 0; nt < 4; ++nt) {
                int n = wc*64 + nt*16 + q15;
                bfr[nt] = *(const short8*)(lB + n*128 + ((s*64 + 16*g) ^ ((n&7)<<4)));
            }
            #pragma unroll
            for (int mt = 0; mt < 4; ++mt)
                #pragma unroll
                for (int nt = 0; nt < 4; ++nt)
                    acc[mt][nt] = __builtin_amdgcn_mfma_f32_16x16x32_bf16(
                        af[mt], bfr[nt], acc[mt][nt], 0, 0, 0);
        }
    }

    #pragma unroll
    for (int mt = 0; mt < 4; ++mt) {
        #pragma unroll
        for (int r = 0; r < 4; ++r) {
            int grow = by*128 + wr*64 + mt*16 + 4*g + r;
            if (MODE == 0) {
                int bb = grow >> 11, ss = grow & (S_-1);
                #pragma unroll
                for (int nt = 0; nt < 4; ++nt) {
                    int n = bx*128 + wc*64 + nt*16 + q15;
                    int hh = n >> 6, dd = n & 63;
                    ((u16*)Out)[(((size_t)bb*NH_ + hh)*S_ + ss)*DH_ + dd] =
                        f2bf(acc[mt][nt][r]);
                }
            } else {
                #pragma unroll
                for (int nt = 0; nt < 4; ++nt) {
                    int n = bx*128 + wc*64 + nt*16 + q15;
                    ((float*)Out)[(size_t)grow * F_ + n] = acc[mt][nt][r];
                }
            }
        }
    }
}

// ---------------------------------------------------------------------------
// V transpose: [b][h][s][d] -> Vt [b][h][d][s] (unchanged).
// ---------------------------------------------------------------------------
__global__ __launch_bounds__(256)
void vtrans(const u16* __restrict__ V, u16* __restrict__ Vt)
{
    __shared__ u16 t[64][66];
    const int tid = threadIdx.x;
    const int st  = blockIdx.x;
    const int bh  = blockIdx.y;

    {
        int s = tid >> 2, dseg = (tid & 3) * 16;
        const u16* src = V + ((size_t)bh*S_ + st*64 + s)*DH_ + dseg;
        short8 a = ((const short8*)src)[0];
        short8 b = ((const short8*)src)[1];
        *(short8*)&t[s][dseg]     = a;
        *(short8*)&t[s][dseg + 8] = b;
    }
    __syncthreads();
    {
        int d = tid >> 2, sseg = (tid & 3) * 16;
        short8 o0, o1;
        #pragma unroll
        for (int i = 0; i < 8; ++i) ((u16*)&o0)[i] = t[sseg + i][d];
        #pragma unroll
        for (int i = 0; i < 8; ++i) ((u16*)&o1)[i] = t[sseg + 8 + i][d];
        u16* dst = Vt + ((size_t)bh*DH_ + d)*S_ + st*64 + sseg;
        ((short8*)dst)[0] = o0;
        ((short8*)dst)[1] = o1;
    }
}

// ---------------------------------------------------------------------------
// attn_v6: cross-iteration pipeline. K+V tiles double-buffered in LDS;
// global loads for kt+1 issued at top of iter kt (reg-staged), LDS writes at
// bottom, ONE barrier per iter. Q,K: [b][h][s][d]; Vt: [b][h][d][s].
// O overwrites own Q rows.
// ---------------------------------------------------------------------------
__global__ __launch_bounds__(256)
void attn_v6(const u16* Q, const u16* __restrict__ K,
             const u16* __restrict__ Vt, u16* O)
{
    __shared__ __align__(16) char vls[2*8192];   // V^T tiles [buf][d][key bytes]
    __shared__ __align__(16) char kls[2*8192];   // K tiles  [buf][key][d bytes]
    __shared__ __align__(16) char pls[4][2048];  // per-wave P [q][key]

    const int tid  = threadIdx.x;
    const int lane = tid & 63;
    const int w    = tid >> 6;
    const int g    = lane >> 4;
    const int q15  = lane & 15;

    const int blk = blockIdx.x;
    const int tq  = blk & 31;
    const int qg  = (tq & 1) ? (31 - (tq >> 1)) : (tq >> 1);
    const int bh  = blk >> 5;
    const int q0  = qg * 64;

    const u16* Kb  = K  + (size_t)bh * S_ * DH_;
    const u16* Vtb = Vt + (size_t)bh * DH_ * S_;

    short8 qf0, qf1;
    {
        const u16* Qp = Q + ((size_t)bh * S_ + q0 + w*16 + q15) * DH_ + g*8;
        qf0 = *(const short8*)(Qp);
        qf1 = *(const short8*)(Qp + 32);
    }

    f32x4 o[4];
    #pragma unroll
    for (int dt = 0; dt < 4; ++dt) o[dt] = (f32x4){0.f,0.f,0.f,0.f};
    float mrow = -1e30f, lrow = 0.f;

    char* plw = (char*)&pls[w][0];
    const int sd = tid >> 2;           // staging row 0..63 (V: d, K: key)
    const int sk = (tid & 3) * 32;     // byte offset in the 128B row

    short8 svv0, svv1, svk0, svk1;     // staged regs for tile kt+1
    auto LOADX = [&](int t) {
        const u16* vs = Vtb + (size_t)sd * S_ + t*64 + (sk >> 1);
        svv0 = ((const short8*)vs)[0];
        svv1 = ((const short8*)vs)[1];
        const u16* ks = Kb + (size_t)(t*64 + sd) * DH_ + (sk >> 1);
        svk0 = ((const short8*)ks)[0];
        svk1 = ((const short8*)ks)[1];
    };
    auto WRITEX = [&](int buf) {
        char* vdst = vls + buf*8192 + sd*128;
        *(short8*)(vdst + ((sk     ) ^ ((sd&7)<<4))) = svv0;
        *(short8*)(vdst + ((sk + 16) ^ ((sd&7)<<4))) = svv1;
        char* kdst = kls + buf*8192 + sd*128;
        *(short8*)(kdst + ((sk     ) ^ ((sd&7)<<4))) = svk0;
        *(short8*)(kdst + ((sk + 16) ^ ((sd&7)<<4))) = svk1;
    };

    // prologue: stage tile 0
    LOADX(0);
    WRITEX(0);
    __syncthreads();

    for (int kt = 0; ; ++kt) {
        const bool more = (kt < qg);
        if (more) LOADX(kt + 1);            // issue next-tile loads (T14)

        const char* kt_ = kls + (kt & 1) * 8192;
        const char* vt_ = vls + (kt & 1) * 8192;

        // ---- QK^T from LDS K tile ----
        float p[16];
        __builtin_amdgcn_s_setprio(1);
        #pragma unroll
        for (int t = 0; t < 4; ++t) {
            int r = t*16 + q15;
            short8 kf0 = *(const short8*)(kt_ + r*128 + ((16*g     ) ^ ((r&7)<<4)));
            short8 kf1 = *(const short8*)(kt_ + r*128 + ((16*g + 64) ^ ((r&7)<<4)));
            f32x4 st = (f32x4){0.f,0.f,0.f,0.f};
            st = __builtin_amdgcn_mfma_f32_16x16x32_bf16(kf0, qf0, st, 0, 0, 0);
            st = __builtin_amdgcn_mfma_f32_16x16x32_bf16(kf1, qf1, st, 0, 0, 0);
            #pragma unroll
            for (int r2 = 0; r2 < 4; ++r2) p[t*4+r2] = st[r2] * 0.125f;
        }
        __builtin_amdgcn_s_setprio(0);

        // causal mask (diagonal tile only)
        if (kt == qg) {
            #pragma unroll
            for (int t = 0; t < 4; ++t)
                #pragma unroll
                for (int r = 0; r < 4; ++r)
                    if (16*t + 4*g + r > w*16 + q15) p[t*4+r] = -1e30f;
        }

        // ---- online softmax ----
        float tmax = p[0];
        #pragma unroll
        for (int i = 1; i < 16; ++i) tmax = fmaxf(tmax, p[i]);
        tmax = fmaxf(tmax, __shfl_xor(tmax, 16));
        tmax = fmaxf(tmax, __shfl_xor(tmax, 32));
        float mnew = fmaxf(mrow, tmax);
        float rsc  = __expf(mrow - mnew);
        mrow = mnew;
        float psum = 0.f;
        #pragma unroll
        for (int i = 0; i < 16; ++i) { p[i] = __expf(p[i] - mnew); psum += p[i]; }
        psum += __shfl_xor(psum, 16);
        psum += __shfl_xor(psum, 32);
        lrow = lrow * rsc + psum;

        #pragma unroll
        for (int r = 0; r < 4; ++r) {
            float rr = __shfl(rsc, 4*g + r);
            #pragma unroll
            for (int dt = 0; dt < 4; ++dt) o[dt][r] *= rr;
        }

        // ---- P -> bf16 -> per-wave LDS ----
        #pragma unroll
        for (int t = 0; t < 4; ++t) {
            ushort4 pw;
            pw.x = f2bf(p[t*4+0]); pw.y = f2bf(p[t*4+1]);
            pw.z = f2bf(p[t*4+2]); pw.w = f2bf(p[t*4+3]);
            int byte = q15*128 + ((32*t + 8*g) ^ ((q15&7)<<4));
            *(ushort4*)(plw + byte) = pw;
        }

        // ---- PV from LDS V^T tile ----
        __builtin_amdgcn_s_setprio(1);
        #pragma unroll
        for (int c = 0; c < 2; ++c) {
            int pb = q15*128 + ((64*c + 16*g) ^ ((q15&7)<<4));
            short8 pf = *(const short8*)(plw + pb);
            #pragma unroll
            for (int dt = 0; dt < 4; ++dt) {
                int d = dt*16 + q15;
                int vb = d*128 + ((64*c + 16*g) ^ ((d&7)<<4));
                short8 vf = *(const short8*)(vt_ + vb);
                o[dt] = __builtin_amdgcn_mfma_f32_16x16x32_bf16(pf, vf, o[dt], 0, 0, 0);
            }
        }
        __builtin_amdgcn_s_setprio(0);

        if (!more) break;
        WRITEX((kt + 1) & 1);               // write staged regs late (T14)
        __syncthreads();                    // one barrier per iteration
    }

    // ---- epilogue ----
    float inv = 1.f / lrow;
    #pragma unroll
    for (int r = 0; r < 4; ++r) {
        float li = __shfl(inv, 4*g + r);
        int qrow = q0 + w*16 + 4*g + r;
        #pragma unroll
        for (int dt = 0; dt < 4; ++dt) {
            O[((size_t)bh * S_ + qrow) * DH_ + dt*16 + q15] = f2bf(o[dt][r] * li);
        }
    }
}

// ---------------------------------------------------------------------------
extern "C" void kernel_launch(void* const* d_in, const int* in_sizes, int n_in,
                              void* d_out, int out_size, void* d_ws, size_t ws_size,
                              hipStream_t stream) {
    (void)in_sizes; (void)n_in; (void)out_size; (void)ws_size;
    const float* x  = (const float*)d_in[0];
    const float* wq = (const float*)d_in[1];
    const float* wk = (const float*)d_in[2];
    const float* wv = (const float*)d_in[3];
    const float* wo = (const float*)d_in[4];

    u16* Qw = (u16*)d_ws;                    // [B][H][S][D] bf16 (O reuses)
    u16* Kw = Qw + (size_t)M_ * F_;
    u16* Vw = Kw + (size_t)M_ * F_;          // ws total 24 MiB
    u16* Vt = (u16*)d_out;                   // scratch; overwritten by oproj

    mfma_gemm<0><<<dim3(F_/128, M_/128, 3), 256, 0, stream>>>(
        (const void*)x, wq, wk, wv, (void*)Qw, (void*)Kw, (void*)Vw);
    vtrans<<<dim3(S_/64, B_*NH_), 256, 0, stream>>>(Vw, Vt);
    attn_v6<<<dim3(B_*NH_*(S_/64)), 256, 0, stream>>>(Qw, Kw, Vt, Qw);
    mfma_gemm<2><<<dim3(F_/128, M_/128, 1), 256, 0, stream>>>(
        (const void*)Qw, wo, wo, wo, d_out, d_out, d_out);
}

// Round 12
// 152.627 us; speedup vs baseline: 1.6921x; 1.2535x over previous
//
#include <hip/hip_runtime.h>
#include <hip/hip_bf16.h>
#include <cstdint>
#include <cstddef>

// Causal self-attention, B=2 S=2048 E=1024 H=16 D=64.
// Inputs fp32, output fp32, ws intermediates bf16.
// Round 12: GEMMs rebuilt on global_load_lds (m97 pattern). One-time prep:
// x -> bf16 rows, W -> bf16 [n][k] transposed (d_out scratch); in-loop fp32
// conversion and reg-staging eliminated. Source-side XOR swizzle (T2) with
// linear LDS. attn_v6 (cross-iter pipeline) + vtrans unchanged from round 11.

#define B_  2
#define S_  2048
#define E_  1024
#define NH_ 16
#define DH_ 64
#define M_  (B_*S_)      // 4096
#define F_  (NH_*DH_)    // 1024

typedef unsigned short u16;
typedef short short8 __attribute__((ext_vector_type(8)));
typedef float f32x4  __attribute__((ext_vector_type(4)));

__device__ __forceinline__ float bf2f(u16 u) {
    union { unsigned int i; float f; } c; c.i = ((unsigned int)u) << 16; return c.f;
}
__device__ __forceinline__ u16 f2bf(float f) {
    union { float f; unsigned int i; } c; c.f = f;
    unsigned int x = c.i;
    x += 0x7fffu + ((x >> 16) & 1u);   // RNE
    return (u16)(x >> 16);
}

// ---------------------------------------------------------------------------
// x fp32 [M][E] -> bf16 rows. 8 elems/thread.
// ---------------------------------------------------------------------------
__global__ __launch_bounds__(256)
void xconv(const float* __restrict__ x, u16* __restrict__ xb)
{
    size_t i = (size_t)blockIdx.x * 256 + threadIdx.x;
    const float4* s = (const float4*)(x + i*8);
    float4 a = s[0], b = s[1];
    short8 o;
    ((u16*)&o)[0] = f2bf(a.x); ((u16*)&o)[1] = f2bf(a.y);
    ((u16*)&o)[2] = f2bf(a.z); ((u16*)&o)[3] = f2bf(a.w);
    ((u16*)&o)[4] = f2bf(b.x); ((u16*)&o)[5] = f2bf(b.y);
    ((u16*)&o)[6] = f2bf(b.z); ((u16*)&o)[7] = f2bf(b.w);
    ((short8*)xb)[i] = o;
}

// ---------------------------------------------------------------------------
// W fp32 [k][n] -> Wt bf16 [n][k]. 64x64 LDS tiles.
// ---------------------------------------------------------------------------
__global__ __launch_bounds__(256)
void wtrans(const float* __restrict__ W, u16* __restrict__ Wt)
{
    __shared__ u16 t[64][66];
    const int tid = threadIdx.x;
    const int n0 = blockIdx.x * 64;
    const int k0 = blockIdx.y * 64;

    {
        int kk = tid >> 2, nseg = (tid & 3) * 16;
        const float4* src = (const float4*)(W + (size_t)(k0+kk)*F_ + n0 + nseg);
        #pragma unroll
        for (int v = 0; v < 4; ++v) {
            float4 u = src[v];
            t[kk][nseg + v*4 + 0] = f2bf(u.x);
            t[kk][nseg + v*4 + 1] = f2bf(u.y);
            t[kk][nseg + v*4 + 2] = f2bf(u.z);
            t[kk][nseg + v*4 + 3] = f2bf(u.w);
        }
    }
    __syncthreads();
    {
        int nn = tid >> 2, kseg = (tid & 3) * 16;
        short8 o0, o1;
        #pragma unroll
        for (int i = 0; i < 8; ++i) ((u16*)&o0)[i] = t[kseg + i][nn];
        #pragma unroll
        for (int i = 0; i < 8; ++i) ((u16*)&o1)[i] = t[kseg + 8 + i][nn];
        u16* dst = Wt + (size_t)(n0+nn)*E_ + k0 + kseg;
        ((short8*)dst)[0] = o0;
        ((short8*)dst)[1] = o1;
    }
}

// ---------------------------------------------------------------------------
// bf16 MFMA GEMM via global_load_lds. 128x128 tile, BK=64, 4 waves (2x2).
// A: MODE 0 = x_bf16 [M][E] rows; MODE 2 = O [b][h][s][d] (BK=64 = one head).
// B: Wt [n][k] bf16 rows (MODE 0: 3 matrices selected by blockIdx.z).
// LDS linear; T2 swizzle applied on the per-lane GLOBAL source chunk.
// ---------------------------------------------------------------------------
template<int MODE>
__global__ __launch_bounds__(256)
void gemm_bf16(const u16* __restrict__ A, const u16* __restrict__ Wt,
               void* __restrict__ Out0, void* __restrict__ Out1,
               void* __restrict__ Out2)
{
    __shared__ __align__(16) char lds[32768];
    char* lA = lds;            // 128 rows * 128 B
    char* lB = lds + 16384;

    const int tid  = threadIdx.x;
    const int lane = tid & 63;
    const int w    = tid >> 6;
    const int wr   = w >> 1, wc = w & 1;
    const int g    = lane >> 4;
    const int q15  = lane & 15;
    const int bx   = blockIdx.x;       // N/128 = 8
    const int by   = blockIdx.y;       // M/128 = 32
    const int z    = (MODE == 0) ? blockIdx.z : 0;

    const u16* Wz  = Wt + (size_t)z * E_ * F_ / 1;   // z * 1024*1024
    void*      Out = (z == 0) ? Out0 : (z == 1) ? Out1 : Out2;

    // gload lane coords: row-within-8 and source chunk (pre-swizzled)
    const int lr  = lane >> 3;             // 0..7
    const int lc  = lane & 7;              // 0..7
    const int swz = ((lc ^ lr) << 4);      // byte offset within 128B row

    const int b2 = by >> 4;                // MODE2: batch
    const int s0 = (by & 15) * 128;        // MODE2: s base

    f32x4 acc[4][4];
    #pragma unroll
    for (int i = 0; i < 4; ++i)
        #pragma unroll
        for (int j = 0; j < 4; ++j) acc[i][j] = (f32x4){0.f,0.f,0.f,0.f};

    for (int it = 0; it < E_/64; ++it) {
        const int k0 = it * 64;
        __syncthreads();                   // prev tile's reads done
        #pragma unroll
        for (int i = 0; i < 4; ++i) {
            const int row = w*32 + i*8 + lr;
            const char* ga;
            if (MODE == 0) {
                ga = (const char*)A + (size_t)(by*128 + row)*2048 + k0*2 + swz;
            } else {
                const int h = k0 >> 6;
                ga = (const char*)A +
                     ((size_t)(b2*NH_ + h)*S_ + s0 + row)*128 + swz;
            }
            __builtin_amdgcn_global_load_lds(
                (const unsigned int*)ga,
                (unsigned int*)(lA + w*4096 + i*1024), 16, 0, 0);
        }
        #pragma unroll
        for (int i = 0; i < 4; ++i) {
            const int row = w*32 + i*8 + lr;
            const char* gb = (const char*)Wz + (size_t)(bx*128 + row)*2048
                             + k0*2 + swz;
            __builtin_amdgcn_global_load_lds(
                (const unsigned int*)gb,
                (unsigned int*)(lB + w*4096 + i*1024), 16, 0, 0);
        }
        __syncthreads();                   // vmcnt drained -> tiles ready

        #pragma unroll
        for (int s = 0; s < 2; ++s) {
            short8 af[4], bfr[4];
            #pragma unroll
            for (int mt = 0; mt < 4; ++mt) {
                int row = wr*64 + mt*16 + q15;
                af[mt] = *(const short8*)(lA + row*128 + ((s*64 + 16*g) ^ ((row&7)<<4)));
            }
            #pragma unroll
            for (int nt = 0; nt < 4; ++nt) {
                int n = wc*64 + nt*16 + q15;
                bfr[nt] = *(const short8*)(lB + n*128 + ((s*64 + 16*g) ^ ((n&7)<<4)));
            }
            #pragma unroll
            for (int mt = 0; mt < 4; ++mt)
                #pragma unroll
                for (int nt = 0; nt < 4; ++nt)
                    acc[mt][nt] = __builtin_amdgcn_mfma_f32_16x16x32_bf16(
                        af[mt], bfr[nt], acc[mt][nt], 0, 0, 0);
        }
    }

    #pragma unroll
    for (int mt = 0; mt < 4; ++mt) {
        #pragma unroll
        for (int r = 0; r < 4; ++r) {
            int grow = by*128 + wr*64 + mt*16 + 4*g + r;
            if (MODE == 0) {
                int bb = grow >> 11, ss = grow & (S_-1);
                #pragma unroll
                for (int nt = 0; nt < 4; ++nt) {
                    int n = bx*128 + wc*64 + nt*16 + q15;
                    int hh = n >> 6, dd = n & 63;
                    ((u16*)Out)[(((size_t)bb*NH_ + hh)*S_ + ss)*DH_ + dd] =
                        f2bf(acc[mt][nt][r]);
                }
            } else {
                #pragma unroll
                for (int nt = 0; nt < 4; ++nt) {
                    int n = bx*128 + wc*64 + nt*16 + q15;
                    ((float*)Out)[(size_t)grow * F_ + n] = acc[mt][nt][r];
                }
            }
        }
    }
}

// ---------------------------------------------------------------------------
// V transpose: [b][h][s][d] -> Vt [b][h][d][s] (unchanged, verified).
// ---------------------------------------------------------------------------
__global__ __launch_bounds__(256)
void vtrans(const u16* __restrict__ V, u16* __restrict__ Vt)
{
    __shared__ u16 t[64][66];
    const int tid = threadIdx.x;
    const int st  = blockIdx.x;
    const int bh  = blockIdx.y;

    {
        int s = tid >> 2, dseg = (tid & 3) * 16;
        const u16* src = V + ((size_t)bh*S_ + st*64 + s)*DH_ + dseg;
        short8 a = ((const short8*)src)[0];
        short8 b = ((const short8*)src)[1];
        *(short8*)&t[s][dseg]     = a;
        *(short8*)&t[s][dseg + 8] = b;
    }
    __syncthreads();
    {
        int d = tid >> 2, sseg = (tid & 3) * 16;
        short8 o0, o1;
        #pragma unroll
        for (int i = 0; i < 8; ++i) ((u16*)&o0)[i] = t[sseg + i][d];
        #pragma unroll
        for (int i = 0; i < 8; ++i) ((u16*)&o1)[i] = t[sseg + 8 + i][d];
        u16* dst = Vt + ((size_t)bh*DH_ + d)*S_ + st*64 + sseg;
        ((short8*)dst)[0] = o0;
        ((short8*)dst)[1] = o1;
    }
}

// ---------------------------------------------------------------------------
// attn_v6 (unchanged from round 11, verified): cross-iteration pipeline,
// K+V double-buffered LDS, loads for kt+1 at top, writes at bottom, 1 barrier.
// ---------------------------------------------------------------------------
__global__ __launch_bounds__(256)
void attn_v6(const u16* Q, const u16* __restrict__ K,
             const u16* __restrict__ Vt, u16* O)
{
    __shared__ __align__(16) char vls[2*8192];
    __shared__ __align__(16) char kls[2*8192];
    __shared__ __align__(16) char pls[4][2048];

    const int tid  = threadIdx.x;
    const int lane = tid & 63;
    const int w    = tid >> 6;
    const int g    = lane >> 4;
    const int q15  = lane & 15;

    const int blk = blockIdx.x;
    const int tq  = blk & 31;
    const int qg  = (tq & 1) ? (31 - (tq >> 1)) : (tq >> 1);
    const int bh  = blk >> 5;
    const int q0  = qg * 64;

    const u16* Kb  = K  + (size_t)bh * S_ * DH_;
    const u16* Vtb = Vt + (size_t)bh * DH_ * S_;

    short8 qf0, qf1;
    {
        const u16* Qp = Q + ((size_t)bh * S_ + q0 + w*16 + q15) * DH_ + g*8;
        qf0 = *(const short8*)(Qp);
        qf1 = *(const short8*)(Qp + 32);
    }

    f32x4 o[4];
    #pragma unroll
    for (int dt = 0; dt < 4; ++dt) o[dt] = (f32x4){0.f,0.f,0.f,0.f};
    float mrow = -1e30f, lrow = 0.f;

    char* plw = (char*)&pls[w][0];
    const int sd = tid >> 2;
    const int sk = (tid & 3) * 32;

    short8 svv0, svv1, svk0, svk1;
    auto LOADX = [&](int t) {
        const u16* vs = Vtb + (size_t)sd * S_ + t*64 + (sk >> 1);
        svv0 = ((const short8*)vs)[0];
        svv1 = ((const short8*)vs)[1];
        const u16* ks = Kb + (size_t)(t*64 + sd) * DH_ + (sk >> 1);
        svk0 = ((const short8*)ks)[0];
        svk1 = ((const short8*)ks)[1];
    };
    auto WRITEX = [&](int buf) {
        char* vdst = vls + buf*8192 + sd*128;
        *(short8*)(vdst + ((sk     ) ^ ((sd&7)<<4))) = svv0;
        *(short8*)(vdst + ((sk + 16) ^ ((sd&7)<<4))) = svv1;
        char* kdst = kls + buf*8192 + sd*128;
        *(short8*)(kdst + ((sk     ) ^ ((sd&7)<<4))) = svk0;
        *(short8*)(kdst + ((sk + 16) ^ ((sd&7)<<4))) = svk1;
    };

    LOADX(0);
    WRITEX(0);
    __syncthreads();

    for (int kt = 0; ; ++kt) {
        const bool more = (kt < qg);
        if (more) LOADX(kt + 1);

        const char* kt_ = kls + (kt & 1) * 8192;
        const char* vt_ = vls + (kt & 1) * 8192;

        float p[16];
        __builtin_amdgcn_s_setprio(1);
        #pragma unroll
        for (int t = 0; t < 4; ++t) {
            int r = t*16 + q15;
            short8 kf0 = *(const short8*)(kt_ + r*128 + ((16*g     ) ^ ((r&7)<<4)));
            short8 kf1 = *(const short8*)(kt_ + r*128 + ((16*g + 64) ^ ((r&7)<<4)));
            f32x4 st = (f32x4){0.f,0.f,0.f,0.f};
            st = __builtin_amdgcn_mfma_f32_16x16x32_bf16(kf0, qf0, st, 0, 0, 0);
            st = __builtin_amdgcn_mfma_f32_16x16x32_bf16(kf1, qf1, st, 0, 0, 0);
            #pragma unroll
            for (int r2 = 0; r2 < 4; ++r2) p[t*4+r2] = st[r2] * 0.125f;
        }
        __builtin_amdgcn_s_setprio(0);

        if (kt == qg) {
            #pragma unroll
            for (int t = 0; t < 4; ++t)
                #pragma unroll
                for (int r = 0; r < 4; ++r)
                    if (16*t + 4*g + r > w*16 + q15) p[t*4+r] = -1e30f;
        }

        float tmax = p[0];
        #pragma unroll
        for (int i = 1; i < 16; ++i) tmax = fmaxf(tmax, p[i]);
        tmax = fmaxf(tmax, __shfl_xor(tmax, 16));
        tmax = fmaxf(tmax, __shfl_xor(tmax, 32));
        float mnew = fmaxf(mrow, tmax);
        float rsc  = __expf(mrow - mnew);
        mrow = mnew;
        float psum = 0.f;
        #pragma unroll
        for (int i = 0; i < 16; ++i) { p[i] = __expf(p[i] - mnew); psum += p[i]; }
        psum += __shfl_xor(psum, 16);
        psum += __shfl_xor(psum, 32);
        lrow = lrow * rsc + psum;

        #pragma unroll
        for (int r = 0; r < 4; ++r) {
            float rr = __shfl(rsc, 4*g + r);
            #pragma unroll
            for (int dt = 0; dt < 4; ++dt) o[dt][r] *= rr;
        }

        #pragma unroll
        for (int t = 0; t < 4; ++t) {
            ushort4 pw;
            pw.x = f2bf(p[t*4+0]); pw.y = f2bf(p[t*4+1]);
            pw.z = f2bf(p[t*4+2]); pw.w = f2bf(p[t*4+3]);
            int byte = q15*128 + ((32*t + 8*g) ^ ((q15&7)<<4));
            *(ushort4*)(plw + byte) = pw;
        }

        __builtin_amdgcn_s_setprio(1);
        #pragma unroll
        for (int c = 0; c < 2; ++c) {
            int pb = q15*128 + ((64*c + 16*g) ^ ((q15&7)<<4));
            short8 pf = *(const short8*)(plw + pb);
            #pragma unroll
            for (int dt = 0; dt < 4; ++dt) {
                int d = dt*16 + q15;
                int vb = d*128 + ((64*c + 16*g) ^ ((d&7)<<4));
                short8 vf = *(const short8*)(vt_ + vb);
                o[dt] = __builtin_amdgcn_mfma_f32_16x16x32_bf16(pf, vf, o[dt], 0, 0, 0);
            }
        }
        __builtin_amdgcn_s_setprio(0);

        if (!more) break;
        WRITEX((kt + 1) & 1);
        __syncthreads();
    }

    float inv = 1.f / lrow;
    #pragma unroll
    for (int r = 0; r < 4; ++r) {
        float li = __shfl(inv, 4*g + r);
        int qrow = q0 + w*16 + 4*g + r;
        #pragma unroll
        for (int dt = 0; dt < 4; ++dt) {
            O[((size_t)bh * S_ + qrow) * DH_ + dt*16 + q15] = f2bf(o[dt][r] * li);
        }
    }
}

// ---------------------------------------------------------------------------
// Scratch layout:
//   ws (24 MiB, proven): Qw[8MB] Kw[8MB] Vw[8MB]   (O reuses Qw; wo^T reuses Vw)
//   d_out (16.78 MB):    D0[0..8MB) = Wt_qkv (6MB) then Vt (8MB, after gemm)
//                        D1[8..16MB) = x_bf16 (8MB)
//   Final gemm overwrites d_out entirely (fp32 result).
// ---------------------------------------------------------------------------
extern "C" void kernel_launch(void* const* d_in, const int* in_sizes, int n_in,
                              void* d_out, int out_size, void* d_ws, size_t ws_size,
                              hipStream_t stream) {
    (void)in_sizes; (void)n_in; (void)out_size; (void)ws_size;
    const float* x  = (const float*)d_in[0];
    const float* wq = (const float*)d_in[1];
    const float* wk = (const float*)d_in[2];
    const float* wv = (const float*)d_in[3];
    const float* wo = (const float*)d_in[4];

    u16* Qw = (u16*)d_ws;
    u16* Kw = Qw + (size_t)M_ * F_;
    u16* Vw = Kw + (size_t)M_ * F_;

    u16* D0 = (u16*)d_out;                       // Wt_qkv, then Vt
    u16* xb = D0 + (size_t)4*1024*1024;          // x_bf16 at byte 8MB

    xconv<<<dim3(M_*E_/8/256), 256, 0, stream>>>(x, xb);
    wtrans<<<dim3(16,16), 256, 0, stream>>>(wq, D0 + 0*(size_t)E_*F_);
    wtrans<<<dim3(16,16), 256, 0, stream>>>(wk, D0 + 1*(size_t)E_*F_);
    wtrans<<<dim3(16,16), 256, 0, stream>>>(wv, D0 + 2*(size_t)E_*F_);

    gemm_bf16<0><<<dim3(F_/128, M_/128, 3), 256, 0, stream>>>(
        xb, D0, (void*)Qw, (void*)Kw, (void*)Vw);

    vtrans<<<dim3(S_/64, B_*NH_), 256, 0, stream>>>(Vw, D0);   // Vt into D0
    wtrans<<<dim3(16,16), 256, 0, stream>>>(wo, Vw);           // wo^T into Vw

    attn_v6<<<dim3(B_*NH_*(S_/64)), 256, 0, stream>>>(Qw, Kw, D0, Qw);

    gemm_bf16<2><<<dim3(F_/128, M_/128, 1), 256, 0, stream>>>(
        Qw, Vw, d_out, d_out, d_out);
}

// Round 13
// 132.016 us; speedup vs baseline: 1.9563x; 1.1561x over previous
//
#include <hip/hip_runtime.h>
#include <hip/hip_bf16.h>
#include <cstdint>
#include <cstddef>

// Causal self-attention, B=2 S=2048 E=1024 H=16 D=64.
// Inputs fp32, output fp32, ws intermediates bf16.
// Round 13: attn_v7 = attn_v6 + (1) LPT dispatch order (heaviest q-tiles
// first: tq=blk>>5, qg=31-tq -> tail backfilled by light blocks) and
// (2) v_cvt_pk_bf16_f32 P-pack (8 HW pack insts replace ~64 VALU RNE ops on
// the serial softmax->PV path). GEMMs/prep unchanged from round 12.

#define B_  2
#define S_  2048
#define E_  1024
#define NH_ 16
#define DH_ 64
#define M_  (B_*S_)      // 4096
#define F_  (NH_*DH_)    // 1024

typedef unsigned short u16;
typedef short short8 __attribute__((ext_vector_type(8)));
typedef float f32x4  __attribute__((ext_vector_type(4)));

__device__ __forceinline__ float bf2f(u16 u) {
    union { unsigned int i; float f; } c; c.i = ((unsigned int)u) << 16; return c.f;
}
__device__ __forceinline__ u16 f2bf(float f) {
    union { float f; unsigned int i; } c; c.f = f;
    unsigned int x = c.i;
    x += 0x7fffu + ((x >> 16) & 1u);   // RNE
    return (u16)(x >> 16);
}

// ---------------------------------------------------------------------------
// x fp32 [M][E] -> bf16 rows. 8 elems/thread. (unchanged)
// ---------------------------------------------------------------------------
__global__ __launch_bounds__(256)
void xconv(const float* __restrict__ x, u16* __restrict__ xb)
{
    size_t i = (size_t)blockIdx.x * 256 + threadIdx.x;
    const float4* s = (const float4*)(x + i*8);
    float4 a = s[0], b = s[1];
    short8 o;
    ((u16*)&o)[0] = f2bf(a.x); ((u16*)&o)[1] = f2bf(a.y);
    ((u16*)&o)[2] = f2bf(a.z); ((u16*)&o)[3] = f2bf(a.w);
    ((u16*)&o)[4] = f2bf(b.x); ((u16*)&o)[5] = f2bf(b.y);
    ((u16*)&o)[6] = f2bf(b.z); ((u16*)&o)[7] = f2bf(b.w);
    ((short8*)xb)[i] = o;
}

// ---------------------------------------------------------------------------
// W fp32 [k][n] -> Wt bf16 [n][k]. 64x64 LDS tiles. (unchanged)
// ---------------------------------------------------------------------------
__global__ __launch_bounds__(256)
void wtrans(const float* __restrict__ W, u16* __restrict__ Wt)
{
    __shared__ u16 t[64][66];
    const int tid = threadIdx.x;
    const int n0 = blockIdx.x * 64;
    const int k0 = blockIdx.y * 64;

    {
        int kk = tid >> 2, nseg = (tid & 3) * 16;
        const float4* src = (const float4*)(W + (size_t)(k0+kk)*F_ + n0 + nseg);
        #pragma unroll
        for (int v = 0; v < 4; ++v) {
            float4 u = src[v];
            t[kk][nseg + v*4 + 0] = f2bf(u.x);
            t[kk][nseg + v*4 + 1] = f2bf(u.y);
            t[kk][nseg + v*4 + 2] = f2bf(u.z);
            t[kk][nseg + v*4 + 3] = f2bf(u.w);
        }
    }
    __syncthreads();
    {
        int nn = tid >> 2, kseg = (tid & 3) * 16;
        short8 o0, o1;
        #pragma unroll
        for (int i = 0; i < 8; ++i) ((u16*)&o0)[i] = t[kseg + i][nn];
        #pragma unroll
        for (int i = 0; i < 8; ++i) ((u16*)&o1)[i] = t[kseg + 8 + i][nn];
        u16* dst = Wt + (size_t)(n0+nn)*E_ + k0 + kseg;
        ((short8*)dst)[0] = o0;
        ((short8*)dst)[1] = o1;
    }
}

// ---------------------------------------------------------------------------
// bf16 MFMA GEMM via global_load_lds. (unchanged from round 12)
// ---------------------------------------------------------------------------
template<int MODE>
__global__ __launch_bounds__(256)
void gemm_bf16(const u16* __restrict__ A, const u16* __restrict__ Wt,
               void* __restrict__ Out0, void* __restrict__ Out1,
               void* __restrict__ Out2)
{
    __shared__ __align__(16) char lds[32768];
    char* lA = lds;
    char* lB = lds + 16384;

    const int tid  = threadIdx.x;
    const int lane = tid & 63;
    const int w    = tid >> 6;
    const int wr   = w >> 1, wc = w & 1;
    const int g    = lane >> 4;
    const int q15  = lane & 15;
    const int bx   = blockIdx.x;
    const int by   = blockIdx.y;
    const int z    = (MODE == 0) ? blockIdx.z : 0;

    const u16* Wz  = Wt + (size_t)z * E_ * F_;
    void*      Out = (z == 0) ? Out0 : (z == 1) ? Out1 : Out2;

    const int lr  = lane >> 3;
    const int lc  = lane & 7;
    const int swz = ((lc ^ lr) << 4);

    const int b2 = by >> 4;
    const int s0 = (by & 15) * 128;

    f32x4 acc[4][4];
    #pragma unroll
    for (int i = 0; i < 4; ++i)
        #pragma unroll
        for (int j = 0; j < 4; ++j) acc[i][j] = (f32x4){0.f,0.f,0.f,0.f};

    for (int it = 0; it < E_/64; ++it) {
        const int k0 = it * 64;
        __syncthreads();
        #pragma unroll
        for (int i = 0; i < 4; ++i) {
            const int row = w*32 + i*8 + lr;
            const char* ga;
            if (MODE == 0) {
                ga = (const char*)A + (size_t)(by*128 + row)*2048 + k0*2 + swz;
            } else {
                const int h = k0 >> 6;
                ga = (const char*)A +
                     ((size_t)(b2*NH_ + h)*S_ + s0 + row)*128 + swz;
            }
            __builtin_amdgcn_global_load_lds(
                (const unsigned int*)ga,
                (unsigned int*)(lA + w*4096 + i*1024), 16, 0, 0);
        }
        #pragma unroll
        for (int i = 0; i < 4; ++i) {
            const int row = w*32 + i*8 + lr;
            const char* gb = (const char*)Wz + (size_t)(bx*128 + row)*2048
                             + k0*2 + swz;
            __builtin_amdgcn_global_load_lds(
                (const unsigned int*)gb,
                (unsigned int*)(lB + w*4096 + i*1024), 16, 0, 0);
        }
        __syncthreads();

        #pragma unroll
        for (int s = 0; s < 2; ++s) {
            short8 af[4], bfr[4];
            #pragma unroll
            for (int mt = 0; mt < 4; ++mt) {
                int row = wr*64 + mt*16 + q15;
                af[mt] = *(const short8*)(lA + row*128 + ((s*64 + 16*g) ^ ((row&7)<<4)));
            }
            #pragma unroll
            for (int nt = 0; nt < 4; ++nt) {
                int n = wc*64 + nt*16 + q15;
                bfr[nt] = *(const short8*)(lB + n*128 + ((s*64 + 16*g) ^ ((n&7)<<4)));
            }
            #pragma unroll
            for (int mt = 0; mt < 4; ++mt)
                #pragma unroll
                for (int nt = 0; nt < 4; ++nt)
                    acc[mt][nt] = __builtin_amdgcn_mfma_f32_16x16x32_bf16(
                        af[mt], bfr[nt], acc[mt][nt], 0, 0, 0);
        }
    }

    #pragma unroll
    for (int mt = 0; mt < 4; ++mt) {
        #pragma unroll
        for (int r = 0; r < 4; ++r) {
            int grow = by*128 + wr*64 + mt*16 + 4*g + r;
            if (MODE == 0) {
                int bb = grow >> 11, ss = grow & (S_-1);
                #pragma unroll
                for (int nt = 0; nt < 4; ++nt) {
                    int n = bx*128 + wc*64 + nt*16 + q15;
                    int hh = n >> 6, dd = n & 63;
                    ((u16*)Out)[(((size_t)bb*NH_ + hh)*S_ + ss)*DH_ + dd] =
                        f2bf(acc[mt][nt][r]);
                }
            } else {
                #pragma unroll
                for (int nt = 0; nt < 4; ++nt) {
                    int n = bx*128 + wc*64 + nt*16 + q15;
                    ((float*)Out)[(size_t)grow * F_ + n] = acc[mt][nt][r];
                }
            }
        }
    }
}

// ---------------------------------------------------------------------------
// V transpose: [b][h][s][d] -> Vt [b][h][d][s] (unchanged, verified).
// ---------------------------------------------------------------------------
__global__ __launch_bounds__(256)
void vtrans(const u16* __restrict__ V, u16* __restrict__ Vt)
{
    __shared__ u16 t[64][66];
    const int tid = threadIdx.x;
    const int st  = blockIdx.x;
    const int bh  = blockIdx.y;

    {
        int s = tid >> 2, dseg = (tid & 3) * 16;
        const u16* src = V + ((size_t)bh*S_ + st*64 + s)*DH_ + dseg;
        short8 a = ((const short8*)src)[0];
        short8 b = ((const short8*)src)[1];
        *(short8*)&t[s][dseg]     = a;
        *(short8*)&t[s][dseg + 8] = b;
    }
    __syncthreads();
    {
        int d = tid >> 2, sseg = (tid & 3) * 16;
        short8 o0, o1;
        #pragma unroll
        for (int i = 0; i < 8; ++i) ((u16*)&o0)[i] = t[sseg + i][d];
        #pragma unroll
        for (int i = 0; i < 8; ++i) ((u16*)&o1)[i] = t[sseg + 8 + i][d];
        u16* dst = Vt + ((size_t)bh*DH_ + d)*S_ + st*64 + sseg;
        ((short8*)dst)[0] = o0;
        ((short8*)dst)[1] = o1;
    }
}

// ---------------------------------------------------------------------------
// attn_v7: attn_v6 + LPT dispatch order + cvt_pk P-pack.
// ---------------------------------------------------------------------------
__global__ __launch_bounds__(256)
void attn_v7(const u16* Q, const u16* __restrict__ K,
             const u16* __restrict__ Vt, u16* O)
{
    __shared__ __align__(16) char vls[2*8192];
    __shared__ __align__(16) char kls[2*8192];
    __shared__ __align__(16) char pls[4][2048];

    const int tid  = threadIdx.x;
    const int lane = tid & 63;
    const int w    = tid >> 6;
    const int g    = lane >> 4;
    const int q15  = lane & 15;

    // LPT: heaviest q-tiles dispatched first; light blocks backfill the tail.
    const int blk = blockIdx.x;
    const int qg  = 31 - (blk >> 5);
    const int bh  = blk & 31;
    const int q0  = qg * 64;

    const u16* Kb  = K  + (size_t)bh * S_ * DH_;
    const u16* Vtb = Vt + (size_t)bh * DH_ * S_;

    short8 qf0, qf1;
    {
        const u16* Qp = Q + ((size_t)bh * S_ + q0 + w*16 + q15) * DH_ + g*8;
        qf0 = *(const short8*)(Qp);
        qf1 = *(const short8*)(Qp + 32);
    }

    f32x4 o[4];
    #pragma unroll
    for (int dt = 0; dt < 4; ++dt) o[dt] = (f32x4){0.f,0.f,0.f,0.f};
    float mrow = -1e30f, lrow = 0.f;

    char* plw = (char*)&pls[w][0];
    const int sd = tid >> 2;
    const int sk = (tid & 3) * 32;

    short8 svv0, svv1, svk0, svk1;
    auto LOADX = [&](int t) {
        const u16* vs = Vtb + (size_t)sd * S_ + t*64 + (sk >> 1);
        svv0 = ((const short8*)vs)[0];
        svv1 = ((const short8*)vs)[1];
        const u16* ks = Kb + (size_t)(t*64 + sd) * DH_ + (sk >> 1);
        svk0 = ((const short8*)ks)[0];
        svk1 = ((const short8*)ks)[1];
    };
    auto WRITEX = [&](int buf) {
        char* vdst = vls + buf*8192 + sd*128;
        *(short8*)(vdst + ((sk     ) ^ ((sd&7)<<4))) = svv0;
        *(short8*)(vdst + ((sk + 16) ^ ((sd&7)<<4))) = svv1;
        char* kdst = kls + buf*8192 + sd*128;
        *(short8*)(kdst + ((sk     ) ^ ((sd&7)<<4))) = svk0;
        *(short8*)(kdst + ((sk + 16) ^ ((sd&7)<<4))) = svk1;
    };

    LOADX(0);
    WRITEX(0);
    __syncthreads();

    for (int kt = 0; ; ++kt) {
        const bool more = (kt < qg);
        if (more) LOADX(kt + 1);

        const char* kt_ = kls + (kt & 1) * 8192;
        const char* vt_ = vls + (kt & 1) * 8192;

        float p[16];
        __builtin_amdgcn_s_setprio(1);
        #pragma unroll
        for (int t = 0; t < 4; ++t) {
            int r = t*16 + q15;
            short8 kf0 = *(const short8*)(kt_ + r*128 + ((16*g     ) ^ ((r&7)<<4)));
            short8 kf1 = *(const short8*)(kt_ + r*128 + ((16*g + 64) ^ ((r&7)<<4)));
            f32x4 st = (f32x4){0.f,0.f,0.f,0.f};
            st = __builtin_amdgcn_mfma_f32_16x16x32_bf16(kf0, qf0, st, 0, 0, 0);
            st = __builtin_amdgcn_mfma_f32_16x16x32_bf16(kf1, qf1, st, 0, 0, 0);
            #pragma unroll
            for (int r2 = 0; r2 < 4; ++r2) p[t*4+r2] = st[r2] * 0.125f;
        }
        __builtin_amdgcn_s_setprio(0);

        if (kt == qg) {
            #pragma unroll
            for (int t = 0; t < 4; ++t)
                #pragma unroll
                for (int r = 0; r < 4; ++r)
                    if (16*t + 4*g + r > w*16 + q15) p[t*4+r] = -1e30f;
        }

        float tmax = p[0];
        #pragma unroll
        for (int i = 1; i < 16; ++i) tmax = fmaxf(tmax, p[i]);
        tmax = fmaxf(tmax, __shfl_xor(tmax, 16));
        tmax = fmaxf(tmax, __shfl_xor(tmax, 32));
        float mnew = fmaxf(mrow, tmax);
        float rsc  = __expf(mrow - mnew);
        mrow = mnew;
        float psum = 0.f;
        #pragma unroll
        for (int i = 0; i < 16; ++i) { p[i] = __expf(p[i] - mnew); psum += p[i]; }
        psum += __shfl_xor(psum, 16);
        psum += __shfl_xor(psum, 32);
        lrow = lrow * rsc + psum;

        #pragma unroll
        for (int r = 0; r < 4; ++r) {
            float rr = __shfl(rsc, 4*g + r);
            #pragma unroll
            for (int dt = 0; dt < 4; ++dt) o[dt][r] *= rr;
        }

        // ---- P -> bf16 via HW pack (RNE), -> per-wave LDS ----
        #pragma unroll
        for (int t = 0; t < 4; ++t) {
            unsigned r0, r1;
            asm("v_cvt_pk_bf16_f32 %0, %1, %2"
                : "=v"(r0) : "v"(p[t*4+0]), "v"(p[t*4+1]));
            asm("v_cvt_pk_bf16_f32 %0, %1, %2"
                : "=v"(r1) : "v"(p[t*4+2]), "v"(p[t*4+3]));
            int byte = q15*128 + ((32*t + 8*g) ^ ((q15&7)<<4));
            uint2 pk; pk.x = r0; pk.y = r1;
            *(uint2*)(plw + byte) = pk;
        }

        __builtin_amdgcn_s_setprio(1);
        #pragma unroll
        for (int c = 0; c < 2; ++c) {
            int pb = q15*128 + ((64*c + 16*g) ^ ((q15&7)<<4));
            short8 pf = *(const short8*)(plw + pb);
            #pragma unroll
            for (int dt = 0; dt < 4; ++dt) {
                int d = dt*16 + q15;
                int vb = d*128 + ((64*c + 16*g) ^ ((d&7)<<4));
                short8 vf = *(const short8*)(vt_ + vb);
                o[dt] = __builtin_amdgcn_mfma_f32_16x16x32_bf16(pf, vf, o[dt], 0, 0, 0);
            }
        }
        __builtin_amdgcn_s_setprio(0);

        if (!more) break;
        WRITEX((kt + 1) & 1);
        __syncthreads();
    }

    float inv = 1.f / lrow;
    #pragma unroll
    for (int r = 0; r < 4; ++r) {
        float li = __shfl(inv, 4*g + r);
        int qrow = q0 + w*16 + 4*g + r;
        #pragma unroll
        for (int dt = 0; dt < 4; ++dt) {
            O[((size_t)bh * S_ + qrow) * DH_ + dt*16 + q15] = f2bf(o[dt][r] * li);
        }
    }
}

// ---------------------------------------------------------------------------
// Scratch layout (unchanged from round 12):
//   ws: Qw[8MB] Kw[8MB] Vw[8MB]; d_out: D0 = Wt_qkv then Vt, D1 = x_bf16.
// ---------------------------------------------------------------------------
extern "C" void kernel_launch(void* const* d_in, const int* in_sizes, int n_in,
                              void* d_out, int out_size, void* d_ws, size_t ws_size,
                              hipStream_t stream) {
    (void)in_sizes; (void)n_in; (void)out_size; (void)ws_size;
    const float* x  = (const float*)d_in[0];
    const float* wq = (const float*)d_in[1];
    const float* wk = (const float*)d_in[2];
    const float* wv = (const float*)d_in[3];
    const float* wo = (const float*)d_in[4];

    u16* Qw = (u16*)d_ws;
    u16* Kw = Qw + (size_t)M_ * F_;
    u16* Vw = Kw + (size_t)M_ * F_;

    u16* D0 = (u16*)d_out;
    u16* xb = D0 + (size_t)4*1024*1024;

    xconv<<<dim3(M_*E_/8/256), 256, 0, stream>>>(x, xb);
    wtrans<<<dim3(16,16), 256, 0, stream>>>(wq, D0 + 0*(size_t)E_*F_);
    wtrans<<<dim3(16,16), 256, 0, stream>>>(wk, D0 + 1*(size_t)E_*F_);
    wtrans<<<dim3(16,16), 256, 0, stream>>>(wv, D0 + 2*(size_t)E_*F_);

    gemm_bf16<0><<<dim3(F_/128, M_/128, 3), 256, 0, stream>>>(
        xb, D0, (void*)Qw, (void*)Kw, (void*)Vw);

    vtrans<<<dim3(S_/64, B_*NH_), 256, 0, stream>>>(Vw, D0);
    wtrans<<<dim3(16,16), 256, 0, stream>>>(wo, Vw);

    attn_v7<<<dim3(B_*NH_*(S_/64)), 256, 0, stream>>>(Qw, Kw, D0, Qw);

    gemm_bf16<2><<<dim3(F_/128, M_/128, 1), 256, 0, stream>>>(
        Qw, Vw, d_out, d_out, d_out);
}